// Round 6
// baseline (1070.198 us; speedup 1.0000x reference)
//
#include <hip/hip_runtime.h>
#include <hip/hip_bf16.h>

// Problem constants: B=4, N=2048, D=1024, H=16, dh=64. All I/O fp32.
#define SEQ   2048
#define DIM   1024
#define HEADS 16
#define DH    64
#define MROWS 8192            // B*N
#define K3    3072            // 3*D
#define NEGV  (-32767.0f)     // -2^15+1, matches reference mask constant
#define SCALE 8.0f            // sqrt(dh) — reference MULTIPLIES by sqrt(d)
#define PLANE ((size_t)MROWS * DIM)   // elements per bf16 plane (8192x1024)

typedef __attribute__((ext_vector_type(8))) short bf16x8;
typedef __attribute__((ext_vector_type(4))) float f32x4;

// scalar bf16 RTNE (epilogue use)
__device__ __forceinline__ short f2bf(float x) {
  union { float f; unsigned u; } v; v.f = x;
  unsigned r = v.u + 0x7FFF + ((v.u >> 16) & 1);
  return (short)(r >> 16);
}
__device__ __forceinline__ float bf2f(short s) {
  union { float f; unsigned u; } v; v.u = ((unsigned)(unsigned short)s) << 16;
  return v.f;
}

// packed HW conversion: 8 floats -> hi bf16x8 (+ lo bf16x8 if dolo)
__device__ __forceinline__ void cvt8(const float4 a, const float4 b,
                                     bf16x8& hi, bf16x8& lo, bool dolo) {
  const float f[8] = {a.x, a.y, a.z, a.w, b.x, b.y, b.z, b.w};
#pragma unroll
  for (int i = 0; i < 4; ++i) {
    __hip_bfloat162 h2 = __float22bfloat162_rn(make_float2(f[2*i], f[2*i+1]));
    const short2 hs = *(const short2*)&h2;
    hi[2*i] = hs.x; hi[2*i+1] = hs.y;
    if (dolo) {
      const float2 hf = __bfloat1622float2(h2);
      __hip_bfloat162 l2 = __float22bfloat162_rn(
          make_float2(f[2*i] - hf.x, f[2*i+1] - hf.y));
      const short2 ls = *(const short2*)&l2;
      lo[2*i] = ls.x; lo[2*i+1] = ls.y;
    }
  }
}

// XOR-swizzled LDS index (shorts) for 64-col row-major tiles: 8-short (16B)
// blocks permuted by row&7 -> ds_read_b128-able fragments, spread banks.
__device__ __forceinline__ int sw(int row, int col) {
  return row * 64 + ((((col >> 3) ^ row) & 7) << 3) + (col & 7);
}

// ---------------------------------------------------------------------------
// Kernel 1: qkv = concat(q,k,v) @ w_qkv^T + b_qkv.
// Q/K cols: split-bf16 3-MFMA compensation; epilogue writes hi/lo bf16 planes.
// V cols: 1-pass; epilogue writes TRANSPOSED bf16 plane Vt[(b,h,d)][n] so
// attention staging needs no transpose/convert.
// ---------------------------------------------------------------------------
__global__ __launch_bounds__(256) void qkv_gemm(
    const float* __restrict__ q,
    const float* __restrict__ k,
    const float* __restrict__ v,
    const float* __restrict__ wqkv,   // (3072, 3072) row-major fp32
    const float* __restrict__ bqkv,   // (3072) fp32
    short* __restrict__ Qh, short* __restrict__ Ql,
    short* __restrict__ Kh, short* __restrict__ Kl,
    short* __restrict__ Vt)           // (4096, 2048) bf16
{
  __shared__ short Ash[128 * 32];
  __shared__ short Asl[128 * 32];
  __shared__ short Bsh[128 * 32];
  __shared__ short Bsl[128 * 32];

  const int t    = threadIdx.x;
  const int lane = t & 63;
  const int wv   = t >> 6;
  const int Mb   = blockIdx.y * 128;
  const int Nb   = blockIdx.x * 128;
  const bool prec = (Nb < 2 * DIM);   // q,k columns need compensation
  const int wr   = (wv >> 1) * 64;
  const int wc   = (wv & 1) * 64;
  const int l15  = lane & 15;
  const int lq   = lane >> 4;
  const int srow = wv * 16 + (lane >> 2);
  const int scol = (lane & 3) * 8;

  f32x4 acc[4][4];
#pragma unroll
  for (int i = 0; i < 4; i++)
#pragma unroll
    for (int j = 0; j < 4; j++) acc[i][j] = (f32x4){0.f, 0.f, 0.f, 0.f};

  for (int k0 = 0; k0 < K3; k0 += 32) {
    const float* src = (k0 < DIM) ? q : ((k0 < 2 * DIM) ? k : v);
    const int koff = (k0 & (DIM - 1)) + scol;

    bf16x8 ah[2], al[2], bh[2], bl[2];
#pragma unroll
    for (int it = 0; it < 2; ++it) {
      const float* ap = src + (size_t)(Mb + it * 64 + srow) * DIM + koff;
      cvt8(*(const float4*)(ap), *(const float4*)(ap + 4), ah[it], al[it], prec);
      const float* bp = wqkv + (size_t)(Nb + it * 64 + srow) * K3 + k0 + scol;
      cvt8(*(const float4*)(bp), *(const float4*)(bp + 4), bh[it], bl[it], prec);
    }
    __syncthreads();
#pragma unroll
    for (int it = 0; it < 2; ++it) {
      *(bf16x8*)(Ash + (it * 64 + srow) * 32 + scol) = ah[it];
      *(bf16x8*)(Bsh + (it * 64 + srow) * 32 + scol) = bh[it];
      if (prec) {
        *(bf16x8*)(Asl + (it * 64 + srow) * 32 + scol) = al[it];
        *(bf16x8*)(Bsl + (it * 64 + srow) * 32 + scol) = bl[it];
      }
    }
    __syncthreads();

    bf16x8 afh[4], bfh[4];
#pragma unroll
    for (int i = 0; i < 4; i++)
      afh[i] = *(const bf16x8*)(Ash + (wr + i * 16 + l15) * 32 + lq * 8);
#pragma unroll
    for (int j = 0; j < 4; j++)
      bfh[j] = *(const bf16x8*)(Bsh + (wc + j * 16 + l15) * 32 + lq * 8);
#pragma unroll
    for (int i = 0; i < 4; i++)
#pragma unroll
      for (int j = 0; j < 4; j++)
        acc[i][j] = __builtin_amdgcn_mfma_f32_16x16x32_bf16(afh[i], bfh[j], acc[i][j], 0, 0, 0);

    if (prec) {
      bf16x8 afl[4], bfl[4];
#pragma unroll
      for (int i = 0; i < 4; i++)
        afl[i] = *(const bf16x8*)(Asl + (wr + i * 16 + l15) * 32 + lq * 8);
#pragma unroll
      for (int j = 0; j < 4; j++)
        bfl[j] = *(const bf16x8*)(Bsl + (wc + j * 16 + l15) * 32 + lq * 8);
#pragma unroll
      for (int i = 0; i < 4; i++)
#pragma unroll
        for (int j = 0; j < 4; j++) {
          acc[i][j] = __builtin_amdgcn_mfma_f32_16x16x32_bf16(afh[i], bfl[j], acc[i][j], 0, 0, 0);
          acc[i][j] = __builtin_amdgcn_mfma_f32_16x16x32_bf16(afl[i], bfh[j], acc[i][j], 0, 0, 0);
        }
    }
  }

  // epilogue: C/D layout col=lane&15, row=(lane>>4)*4+reg  [m89/m91 verified]
#pragma unroll
  for (int j = 0; j < 4; j++) {
    const int col = Nb + wc + j * 16 + l15;
    const float bias = bqkv[col];
#pragma unroll
    for (int i = 0; i < 4; i++) {
#pragma unroll
      for (int r = 0; r < 4; r++) {
        const int row = Mb + wr + i * 16 + lq * 4 + r;
        const float val = acc[i][j][r] + bias;
        if (Nb < DIM) {                      // Q plane, hi/lo
          const short hi = f2bf(val);
          Qh[(size_t)row * DIM + col] = hi;
          Ql[(size_t)row * DIM + col] = f2bf(val - bf2f(hi));
        } else if (Nb < 2 * DIM) {           // K plane, hi/lo
          const int c = col - DIM;
          const short hi = f2bf(val);
          Kh[(size_t)row * DIM + c] = hi;
          Kl[(size_t)row * DIM + c] = f2bf(val - bf2f(hi));
        } else {                             // V -> transposed bf16 plane
          const int c = col - 2 * DIM;       // h*64 + d
          const int bb = row >> 11, n = row & (SEQ - 1);
          Vt[(size_t)((bb * HEADS) << 6) * SEQ + (size_t)c * SEQ + n] = f2bf(val);
        }
      }
    }
  }
}

// stage 64x64 bf16 tile (row stride gs shorts) -> swizzled LDS, no convert.
// thread t: row=t>>2, cols (t&3)*16..+16 — 2 x 16B loads, 2 x 16B LDS stores.
__device__ __forceinline__ void stage_bf(const short* __restrict__ g0, int gs,
                                         short* dst, int t) {
  const int row = t >> 2;
  const int cb  = (t & 3) * 16;
  const short* gp = g0 + (size_t)row * gs + cb;
  const bf16x8 a = *(const bf16x8*)(gp);
  const bf16x8 b = *(const bf16x8*)(gp + 8);
  *(bf16x8*)(dst + sw(row, cb))     = a;
  *(bf16x8*)(dst + sw(row, cb + 8)) = b;
}

// ---------------------------------------------------------------------------
// Kernel 2: MFMA flash attention on pre-split planes. Block=(b,h,64-q-tile),
// 4 waves. QK^T split-bf16 3-MFMA; PV 1-pass bf16 via P->LDS round-trip and
// pre-transposed V plane. Staging: pure 16B copies into swizzled LDS.
// ---------------------------------------------------------------------------
__global__ __launch_bounds__(256) void attn_fwd(
    const short* __restrict__ QhP, const short* __restrict__ QlP,
    const short* __restrict__ KhP, const short* __restrict__ KlP,
    const short* __restrict__ VtP,          // (4096, 2048) bf16
    __hip_bfloat16* __restrict__ attno)     // (8192, 1024) bf16
{
  __shared__ short Qh[4096], Ql[4096], Kh[4096], Kl[4096], Vs[4096];
  __shared__ short Ps[4][1024];             // per-wave 16x64 P tile

  const int bx = blockIdx.x;
  const int qt = 31 - (bx & 31);            // heavy q-tiles dispatch first
  const int h  = (bx >> 5) & 15;
  const int b  = bx >> 9;
  const int qb = qt * 64;

  const int t    = threadIdx.x;
  const int lane = t & 63;
  const int wv   = t >> 6;
  const int l15  = lane & 15;
  const int quad = lane >> 4;
  const size_t rowBase = (size_t)b * SEQ;

  stage_bf(QhP + (rowBase + qb) * DIM + h * DH, DIM, Qh, t);
  stage_bf(QlP + (rowBase + qb) * DIM + h * DH, DIM, Ql, t);
  __syncthreads();

  // Q A-fragments: A[m=l15][k=ks*32+quad*8+j], rows 16*wv + l15 (load once)
  bf16x8 qah[2], qal[2];
#pragma unroll
  for (int ks = 0; ks < 2; ++ks) {
    qah[ks] = *(const bf16x8*)(Qh + sw(16 * wv + l15, ks * 32 + quad * 8));
    qal[ks] = *(const bf16x8*)(Ql + sw(16 * wv + l15, ks * 32 + quad * 8));
  }

  float m_i[4], l_i[4];
  f32x4 O[4];
#pragma unroll
  for (int r = 0; r < 4; ++r) { m_i[r] = -1e30f; l_i[r] = 0.f; }
#pragma unroll
  for (int jd = 0; jd < 4; ++jd) O[jd] = (f32x4){0.f, 0.f, 0.f, 0.f};

  const short* vbase = VtP + (size_t)((b * HEADS + h) * DH) * SEQ;

  const int nkt = qt + 1;                   // causal: keys <= qb+63
  for (int kt = 0; kt < nkt; ++kt) {
    const int kb = kt * 64;
    __syncthreads();                        // prev tile's fragment reads done
    stage_bf(KhP + (rowBase + kb) * DIM + h * DH, DIM, Kh, t);
    stage_bf(KlP + (rowBase + kb) * DIM + h * DH, DIM, Kl, t);
    stage_bf(vbase + kb, SEQ, Vs, t);       // Vs[d][key], already transposed
    __syncthreads();                        // staging visible

    // ---- S = Q K^T, 4 n-tiles of 16 keys, split-bf16 (hh + lh + hl) ----
    f32x4 s[4];
#pragma unroll
    for (int j = 0; j < 4; ++j) s[j] = (f32x4){0.f, 0.f, 0.f, 0.f};
#pragma unroll
    for (int j = 0; j < 4; ++j) {
#pragma unroll
      for (int ks = 0; ks < 2; ++ks) {
        const bf16x8 kh = *(const bf16x8*)(Kh + sw(16 * j + l15, ks * 32 + quad * 8));
        const bf16x8 kl = *(const bf16x8*)(Kl + sw(16 * j + l15, ks * 32 + quad * 8));
        s[j] = __builtin_amdgcn_mfma_f32_16x16x32_bf16(qah[ks], kh, s[j], 0, 0, 0);
        s[j] = __builtin_amdgcn_mfma_f32_16x16x32_bf16(qal[ks], kh, s[j], 0, 0, 0);
        s[j] = __builtin_amdgcn_mfma_f32_16x16x32_bf16(qah[ks], kl, s[j], 0, 0, 0);
      }
    }

    // ---- scale, causal mask, online softmax (C-layout registers) ----
    const int qrow0 = qb + 16 * wv + 4 * quad;
    float p[4][4];
    float mt[4] = {-1e30f, -1e30f, -1e30f, -1e30f};
#pragma unroll
    for (int j = 0; j < 4; ++j) {
      const int key = kb + 16 * j + l15;
#pragma unroll
      for (int r = 0; r < 4; ++r) {
        float sv = s[j][r] * SCALE;
        if (key > qrow0 + r) sv = NEGV;
        p[j][r] = sv;
        mt[r] = fmaxf(mt[r], sv);
      }
    }
#pragma unroll
    for (int r = 0; r < 4; ++r) {
      mt[r] = fmaxf(mt[r], __shfl_xor(mt[r], 1));
      mt[r] = fmaxf(mt[r], __shfl_xor(mt[r], 2));
      mt[r] = fmaxf(mt[r], __shfl_xor(mt[r], 4));
      mt[r] = fmaxf(mt[r], __shfl_xor(mt[r], 8));
    }
    float alpha[4];
#pragma unroll
    for (int r = 0; r < 4; ++r) {
      const float mn = fmaxf(m_i[r], mt[r]);
      alpha[r] = __expf(m_i[r] - mn);
      m_i[r] = mn;
    }
    float ls[4] = {0.f, 0.f, 0.f, 0.f};
#pragma unroll
    for (int j = 0; j < 4; ++j)
#pragma unroll
      for (int r = 0; r < 4; ++r) {
        p[j][r] = __expf(p[j][r] - m_i[r]);
        ls[r] += p[j][r];
      }
#pragma unroll
    for (int r = 0; r < 4; ++r) {
      ls[r] += __shfl_xor(ls[r], 1);
      ls[r] += __shfl_xor(ls[r], 2);
      ls[r] += __shfl_xor(ls[r], 4);
      ls[r] += __shfl_xor(ls[r], 8);
      l_i[r] = l_i[r] * alpha[r] + ls[r];
    }
#pragma unroll
    for (int jd = 0; jd < 4; ++jd)
#pragma unroll
      for (int r = 0; r < 4; ++r) O[jd][r] *= alpha[r];

    // ---- P (C-layout) -> per-wave LDS (swizzled row-major 16x64) ----
#pragma unroll
    for (int j = 0; j < 4; ++j)
#pragma unroll
      for (int r = 0; r < 4; ++r)
        Ps[wv][sw(4 * quad + r, 16 * j + l15)] = f2bf(p[j][r]);
    __syncthreads();                        // P visible (conservative)

    // ---- O += P V : A = P (A-layout reload), B = Vs (transposed V) ----
#pragma unroll
    for (int ks = 0; ks < 2; ++ks) {
      const bf16x8 pa = *(const bf16x8*)(&Ps[wv][sw(l15, ks * 32 + quad * 8)]);
#pragma unroll
      for (int jd = 0; jd < 4; ++jd) {
        const bf16x8 vb = *(const bf16x8*)(Vs + sw(16 * jd + l15, ks * 32 + quad * 8));
        O[jd] = __builtin_amdgcn_mfma_f32_16x16x32_bf16(pa, vb, O[jd], 0, 0, 0);
      }
    }
  }

  // epilogue: O/l -> bf16 attn ws (C-layout scatter, once per block)
#pragma unroll
  for (int jd = 0; jd < 4; ++jd) {
#pragma unroll
    for (int r = 0; r < 4; ++r) {
      const int row = qb + 16 * wv + 4 * quad + r;
      attno[(rowBase + row) * DIM + h * DH + 16 * jd + l15] =
          __float2bfloat16(O[jd][r] / l_i[r]);
    }
  }
}

// ---------------------------------------------------------------------------
// Kernel 3 (unchanged): out = attn @ w_out^T + b_out
// ---------------------------------------------------------------------------
__global__ __launch_bounds__(256) void out_gemm(
    const __hip_bfloat16* __restrict__ a,    // (8192, 1024) attn, bf16
    const float* __restrict__ wo,            // (1024, 1024) fp32
    const float* __restrict__ bo,            // (1024) fp32
    float* __restrict__ out)                 // (8192, 1024) fp32
{
  __shared__ short As[128 * 32];
  __shared__ short Bs[128 * 32];

  const int t    = threadIdx.x;
  const int lane = t & 63;
  const int wv   = t >> 6;
  const int Mb   = blockIdx.y * 128;
  const int Nb   = blockIdx.x * 128;
  const int wr   = (wv >> 1) * 64;
  const int wc   = (wv & 1) * 64;
  const int l15  = lane & 15;
  const int lq   = lane >> 4;
  const int srow = wv * 16 + (lane >> 2);
  const int scol = (lane & 3) * 8;

  f32x4 acc[4][4];
#pragma unroll
  for (int i = 0; i < 4; i++)
#pragma unroll
    for (int j = 0; j < 4; j++) acc[i][j] = (f32x4){0.f, 0.f, 0.f, 0.f};

  for (int k0 = 0; k0 < DIM; k0 += 32) {
    bf16x8 areg[2], breg[2], dummy;
#pragma unroll
    for (int it = 0; it < 2; ++it) {
      areg[it] = *(const bf16x8*)(a + (size_t)(Mb + it * 64 + srow) * DIM + k0 + scol);
      const float* bp = wo + (size_t)(Nb + it * 64 + srow) * DIM + k0 + scol;
      cvt8(*(const float4*)(bp), *(const float4*)(bp + 4), breg[it], dummy, false);
    }
    __syncthreads();
#pragma unroll
    for (int it = 0; it < 2; ++it) {
      *(bf16x8*)(As + (it * 64 + srow) * 32 + scol) = areg[it];
      *(bf16x8*)(Bs + (it * 64 + srow) * 32 + scol) = breg[it];
    }
    __syncthreads();

    bf16x8 af[4], bfr[4];
#pragma unroll
    for (int i = 0; i < 4; i++)
      af[i] = *(const bf16x8*)(As + (wr + i * 16 + l15) * 32 + lq * 8);
#pragma unroll
    for (int j = 0; j < 4; j++)
      bfr[j] = *(const bf16x8*)(Bs + (wc + j * 16 + l15) * 32 + lq * 8);
#pragma unroll
    for (int i = 0; i < 4; i++)
#pragma unroll
      for (int j = 0; j < 4; j++)
        acc[i][j] = __builtin_amdgcn_mfma_f32_16x16x32_bf16(af[i], bfr[j], acc[i][j], 0, 0, 0);
  }

#pragma unroll
  for (int j = 0; j < 4; j++) {
    const int col = Nb + wc + j * 16 + l15;
    const float bias = bo[col];
#pragma unroll
    for (int i = 0; i < 4; i++) {
#pragma unroll
      for (int r = 0; r < 4; r++) {
        const int row = Mb + wr + i * 16 + lq * 4 + r;
        out[(size_t)row * DIM + col] = acc[i][j][r] + bias;
      }
    }
  }
}

// ---------------------------------------------------------------------------
extern "C" void kernel_launch(void* const* d_in, const int* in_sizes, int n_in,
                              void* d_out, int out_size, void* d_ws, size_t ws_size,
                              hipStream_t stream) {
  const float* q    = (const float*)d_in[0];
  const float* k    = (const float*)d_in[1];
  const float* v    = (const float*)d_in[2];
  const float* wqkv = (const float*)d_in[3];
  const float* bqkv = (const float*)d_in[4];
  const float* wout = (const float*)d_in[5];
  const float* bout = (const float*)d_in[6];

  // ws layout: 6 bf16 planes of 8192x1024 (16.78 MB each) = 100.7 MB total
  short* Qh = (short*)d_ws;
  short* Ql = Qh + PLANE;
  short* Kh = Ql + PLANE;
  short* Kl = Kh + PLANE;
  short* Vt = Kl + PLANE;                       // viewed as (4096, 2048)
  __hip_bfloat16* attnws = (__hip_bfloat16*)(Vt + PLANE);

  qkv_gemm<<<dim3(K3 / 128, MROWS / 128), 256, 0, stream>>>(
      q, k, v, wqkv, bqkv, Qh, Ql, Kh, Kl, Vt);
  attn_fwd<<<dim3(4 * HEADS * (SEQ / 64)), 256, 0, stream>>>(
      Qh, Ql, Kh, Kl, Vt, attnws);
  out_gemm<<<dim3(DIM / 128, MROWS / 128), 256, 0, stream>>>(attnws, wout, bout,
                                                             (float*)d_out);
}